// Round 1
// baseline (2068.031 us; speedup 1.0000x reference)
//
#include <hip/hip_runtime.h>

#define D 64

// ---------------------------------------------------------------- zero fill
__global__ __launch_bounds__(256) void k_zero(float* __restrict__ p, long n) {
    long i = (long)blockIdx.x * blockDim.x + threadIdx.x;
    long stride = (long)gridDim.x * blockDim.x;
    long n4 = n >> 2;
    float4* p4 = (float4*)p;
    for (long j = i; j < n4; j += stride) p4[j] = make_float4(0.f, 0.f, 0.f, 0.f);
    // scalar tail
    long tail = n4 << 2;
    for (long j = tail + i; j < n; j += stride) p[j] = 0.f;
}

// ------------------------------------------------- Y = X @ W + b, opt. relu
// one wave per row; W (64x64 f32 = 16 KB) staged in LDS per block
__global__ __launch_bounds__(256) void k_linear(const float* __restrict__ X,
                                                const float* __restrict__ W,
                                                const float* __restrict__ b,
                                                float* __restrict__ Y,
                                                int nrows, int do_relu) {
    __shared__ float Wl[D * D];
    __shared__ float bl[D];
    for (int i = threadIdx.x; i < D * D; i += 256) Wl[i] = W[i];
    if (threadIdx.x < D) bl[threadIdx.x] = b[threadIdx.x];
    __syncthreads();
    int lane = threadIdx.x & 63;
    int lrow = threadIdx.x >> 6;
    for (int row = blockIdx.x * 4 + lrow; row < nrows; row += gridDim.x * 4) {
        const float4* x4 = (const float4*)(X + (long)row * D);
        float acc = bl[lane];
#pragma unroll
        for (int k4 = 0; k4 < D / 4; ++k4) {
            float4 xv = x4[k4];  // uniform across the wave -> broadcast
            acc += xv.x * Wl[(k4 * 4 + 0) * D + lane];
            acc += xv.y * Wl[(k4 * 4 + 1) * D + lane];
            acc += xv.z * Wl[(k4 * 4 + 2) * D + lane];
            acc += xv.w * Wl[(k4 * 4 + 3) * D + lane];
        }
        if (do_relu) acc = fmaxf(acc, 0.f);
        Y[(long)row * D + lane] = acc;
    }
}

// -------------------------------- edge scatter: acc[dst] += src[srcIdx], cnt
// 64 lanes per edge (one per feature element)
__global__ __launch_bounds__(256) void k_scatter(const float* __restrict__ src,
                                                 const int* __restrict__ src_idx,
                                                 const int* __restrict__ dst_idx,
                                                 float* __restrict__ acc,
                                                 float* __restrict__ cnt,
                                                 int nedges) {
    long i = (long)blockIdx.x * blockDim.x + threadIdx.x;
    long stride = (long)gridDim.x * blockDim.x;
    long total = (long)nedges * D;
    for (; i < total; i += stride) {
        int e = (int)(i >> 6);
        int lane = (int)(i & 63);
        int s = src_idx[e];
        int d = dst_idx[e];
        float v = src[(long)s * D + lane];
        atomicAdd(&acc[(long)d * D + lane], v);
        if (lane == 0) atomicAdd(&cnt[d], 1.0f);
    }
}

// ---------- clause finalize: mean -> relu -> @W_c2l + b, in place over AC
__global__ __launch_bounds__(256) void k_clause_fin(float* __restrict__ AC,
                                                    const float* __restrict__ cnt,
                                                    const float* __restrict__ W,
                                                    const float* __restrict__ b,
                                                    int nrows) {
    __shared__ float Wl[D * D];
    __shared__ float bl[D];
    for (int i = threadIdx.x; i < D * D; i += 256) Wl[i] = W[i];
    if (threadIdx.x < D) bl[threadIdx.x] = b[threadIdx.x];
    __syncthreads();
    int lane = threadIdx.x & 63;
    int lrow = threadIdx.x >> 6;
    for (int row = blockIdx.x * 4 + lrow; row < nrows; row += gridDim.x * 4) {
        float c = AC[(long)row * D + lane];
        float n = cnt[row];
        c = c / fmaxf(n, 1.0f);
        c = fmaxf(c, 0.f);          // relu -> cembs element for this lane
        float acc = bl[lane];
#pragma unroll
        for (int k = 0; k < D; ++k) {
            acc += __shfl(c, k) * Wl[k * D + lane];  // readlane broadcast
        }
        AC[(long)row * D + lane] = acc;  // in place: wave read its row already
    }
}

// -------------------------------------- divide h_lit accumulator by counts
__global__ __launch_bounds__(256) void k_lit_fin(float* __restrict__ out,
                                                 const float* __restrict__ cnt,
                                                 long n) {
    long i = (long)blockIdx.x * blockDim.x + threadIdx.x;
    long stride = (long)gridDim.x * blockDim.x;
    for (; i < n; i += stride) {
        int row = (int)(i >> 6);
        out[i] = out[i] / fmaxf(cnt[row], 1.0f);
    }
}

extern "C" void kernel_launch(void* const* d_in, const int* in_sizes, int n_in,
                              void* d_out, int out_size, void* d_ws, size_t ws_size,
                              hipStream_t stream) {
    const float* feat_lit = (const float*)d_in[0];
    const float* feat_cls = (const float*)d_in[1];
    const int*   lit_idx  = (const int*)d_in[2];
    const int*   cls_idx  = (const int*)d_in[3];
    const float* W_l2c    = (const float*)d_in[4];
    const float* b_l2c    = (const float*)d_in[5];
    const float* W_c2l    = (const float*)d_in[6];
    const float* b_c2l    = (const float*)d_in[7];

    const int n_lit   = in_sizes[0] / D;
    const int n_cls   = in_sizes[1] / D;
    const int n_edges = in_sizes[2];

    float* out_hlit = (float*)d_out;                      // [n_lit, D]
    float* out_h2   = out_hlit + (long)n_lit * D;         // [n_cls, D]

    // workspace layout (f32): Wh_l2c | clause_acc (reused as Wh_c2l) | cnt_cls | cnt_lit
    float* ws0 = (float*)d_ws;                  // n_lit * D
    float* ws1 = ws0 + (long)n_lit * D;         // n_cls * D
    float* ws2 = ws1 + (long)n_cls * D;         // n_cls
    float* ws3 = ws2 + n_cls;                   // n_lit

    const int GB = 2048, BT = 256;

    // zero: clause acc + both counts (contiguous), and h_lit region of d_out
    long zn1 = (long)n_cls * D + n_cls + n_lit;
    k_zero<<<GB, BT, 0, stream>>>(ws1, zn1);
    k_zero<<<GB, BT, 0, stream>>>(out_hlit, (long)n_lit * D);

    // linear layers sharing W_l2c
    k_linear<<<GB, BT, 0, stream>>>(feat_lit, W_l2c, b_l2c, ws0, n_lit, 0);
    k_linear<<<GB, BT, 0, stream>>>(feat_cls, W_l2c, b_l2c, out_h2, n_cls, 1);

    // l2c mean aggregation
    k_scatter<<<GB, BT, 0, stream>>>(ws0, lit_idx, cls_idx, ws1, ws2, n_edges);

    // clause mean -> relu -> @W_c2l + b (in place in ws1)
    k_clause_fin<<<GB, BT, 0, stream>>>(ws1, ws2, W_c2l, b_c2l, n_cls);

    // c2l mean aggregation straight into d_out
    k_scatter<<<GB, BT, 0, stream>>>(ws1, cls_idx, lit_idx, out_hlit, ws3, n_edges);
    k_lit_fin<<<GB, BT, 0, stream>>>(out_hlit, ws3, (long)n_lit * D);
}

// Round 2
// 1627.288 us; speedup vs baseline: 1.2708x; 1.2708x over previous
//
#include <hip/hip_runtime.h>

#define D 64

// ---------------------------------------------------------------- zero fill
__global__ __launch_bounds__(256) void k_zero(float* __restrict__ p, long n) {
    long i = (long)blockIdx.x * blockDim.x + threadIdx.x;
    long stride = (long)gridDim.x * blockDim.x;
    long n4 = n >> 2;
    float4* p4 = (float4*)p;
    for (long j = i; j < n4; j += stride) p4[j] = make_float4(0.f, 0.f, 0.f, 0.f);
    long tail = n4 << 2;
    for (long j = tail + i; j < n; j += stride) p[j] = 0.f;
}

// ---------------------------------------------------- degree histogram (int)
__global__ __launch_bounds__(256) void k_hist(const int* __restrict__ lit_idx,
                                              const int* __restrict__ cls_idx,
                                              int* __restrict__ cnt,  // [n_cls + n_lit]
                                              int n_edges, int n_cls) {
    long i = (long)blockIdx.x * blockDim.x + threadIdx.x;
    long stride = (long)gridDim.x * blockDim.x;
    for (; i < n_edges; i += stride) {
        atomicAdd(&cnt[cls_idx[i]], 1);
        atomicAdd(&cnt[n_cls + lit_idx[i]], 1);
    }
}

// ------------------- hierarchical exclusive scan: pass 1 (4096 elems/block)
__global__ __launch_bounds__(256) void k_scan1(int* __restrict__ data,   // in-place cnt -> excl scan (block-local)
                                               int* __restrict__ partial,
                                               int n) {
    __shared__ int wsum[4];
    int base = blockIdx.x * 4096 + threadIdx.x * 16;
    int v[16];
    int tsum = 0;
#pragma unroll
    for (int j = 0; j < 16; ++j) {
        int idx = base + j;
        v[j] = (idx < n) ? data[idx] : 0;
        tsum += v[j];
    }
    int lane = threadIdx.x & 63;
    int wid = threadIdx.x >> 6;
    int incl = tsum;
    for (int d = 1; d < 64; d <<= 1) {
        int t = __shfl_up(incl, d);
        if (lane >= d) incl += t;
    }
    if (lane == 63) wsum[wid] = incl;
    __syncthreads();
    int wbase = 0;
    for (int w = 0; w < wid; ++w) wbase += wsum[w];
    int run = wbase + incl - tsum;  // exclusive prefix of this thread within block
#pragma unroll
    for (int j = 0; j < 16; ++j) {
        int idx = base + j;
        if (idx < n) data[idx] = run;
        run += v[j];
    }
    if (threadIdx.x == 255) partial[blockIdx.x] = wbase + incl;  // block total
}

// ---------------- scan pass 2: single block scans partials (nb <= 256)
__global__ __launch_bounds__(256) void k_scan2(int* __restrict__ partial, int nb,
                                               int* __restrict__ off, int n) {
    __shared__ int wsum[4];
    int tid = threadIdx.x;
    int v = (tid < nb) ? partial[tid] : 0;
    int lane = tid & 63, wid = tid >> 6;
    int incl = v;
    for (int d = 1; d < 64; d <<= 1) {
        int t = __shfl_up(incl, d);
        if (lane >= d) incl += t;
    }
    if (lane == 63) wsum[wid] = incl;
    __syncthreads();
    int wbase = 0;
    for (int w = 0; w < wid; ++w) wbase += wsum[w];
    if (tid < nb) partial[tid] = wbase + incl - v;  // exclusive
    if (tid == 255) off[n] = wbase + incl;          // grand total sentinel
}

// ---------------- scan pass 3: add block offsets; also copy to cursor
__global__ __launch_bounds__(256) void k_scan3(int* __restrict__ off,
                                               const int* __restrict__ partial,
                                               int* __restrict__ cursor, int n) {
    long i = (long)blockIdx.x * blockDim.x + threadIdx.x;
    long stride = (long)gridDim.x * blockDim.x;
    for (; i < n; i += stride) {
        int o = off[i] + partial[i >> 12];
        off[i] = o;
        cursor[i] = o;
    }
}

// ---------------- fill both CSR edge lists
__global__ __launch_bounds__(256) void k_fill(const int* __restrict__ lit_idx,
                                              const int* __restrict__ cls_idx,
                                              int* __restrict__ cursor,
                                              int* __restrict__ edge_buf,
                                              int n_edges, int n_cls) {
    long i = (long)blockIdx.x * blockDim.x + threadIdx.x;
    long stride = (long)gridDim.x * blockDim.x;
    for (; i < n_edges; i += stride) {
        int l = lit_idx[i], c = cls_idx[i];
        int p = atomicAdd(&cursor[c], 1);
        edge_buf[p] = l;
        int q = atomicAdd(&cursor[n_cls + l], 1);
        edge_buf[q] = c;
    }
}

// ------------------------------------------------- Y = X @ W + b, opt. relu
__global__ __launch_bounds__(256) void k_linear(const float* __restrict__ X,
                                                const float* __restrict__ W,
                                                const float* __restrict__ b,
                                                float* __restrict__ Y,
                                                int nrows, int do_relu) {
    __shared__ float Wl[D * D];
    __shared__ float bl[D];
    for (int i = threadIdx.x; i < D * D; i += 256) Wl[i] = W[i];
    if (threadIdx.x < D) bl[threadIdx.x] = b[threadIdx.x];
    __syncthreads();
    int lane = threadIdx.x & 63;
    int lrow = threadIdx.x >> 6;
    for (int row = blockIdx.x * 4 + lrow; row < nrows; row += gridDim.x * 4) {
        const float4* x4 = (const float4*)(X + (long)row * D);
        float acc = bl[lane];
#pragma unroll
        for (int k4 = 0; k4 < D / 4; ++k4) {
            float4 xv = x4[k4];
            acc += xv.x * Wl[(k4 * 4 + 0) * D + lane];
            acc += xv.y * Wl[(k4 * 4 + 1) * D + lane];
            acc += xv.z * Wl[(k4 * 4 + 2) * D + lane];
            acc += xv.w * Wl[(k4 * 4 + 3) * D + lane];
        }
        if (do_relu) acc = fmaxf(acc, 0.f);
        Y[(long)row * D + lane] = acc;
    }
}

// ------- gather-mean over CSR row, then fused 64x64 linear (+opt relu)
// one wave per output row
__global__ __launch_bounds__(256) void k_agg(const float* __restrict__ src,
                                             const int* __restrict__ off,    // [nrows+1] (region-local)
                                             const int* __restrict__ edges,  // global edge buf
                                             const float* __restrict__ W,
                                             const float* __restrict__ bias,
                                             float* __restrict__ out,
                                             int nrows, int relu_out) {
    __shared__ float Wl[D * D];
    __shared__ float bl[D];
    for (int i = threadIdx.x; i < D * D; i += 256) Wl[i] = W[i];
    if (threadIdx.x < D) bl[threadIdx.x] = bias[threadIdx.x];
    __syncthreads();
    int lane = threadIdx.x & 63;
    int wrow = threadIdx.x >> 6;
    int row = blockIdx.x * 4 + wrow;
    if (row >= nrows) return;
    int s = off[row], e = off[row + 1];
    int cnt = e - s;
    float acc = 0.f;
    for (int base = s; base < e; base += 64) {
        int nn = min(64, e - base);
        int myidx = (base + lane < e) ? edges[base + lane] : 0;
        for (int j = 0; j < nn; ++j) {
            int c = __shfl(myidx, j);
            acc += src[(long)c * D + lane];
        }
    }
    float m = (cnt > 0) ? acc / (float)cnt : 0.f;
    float y = bl[lane];
#pragma unroll
    for (int k = 0; k < D; ++k) y += __shfl(m, k) * Wl[k * D + lane];
    if (cnt == 0) y = 0.f;  // reference: empty segment -> exact zero (pre-relu h = 0)
    if (relu_out) y = fmaxf(y, 0.f);
    out[(long)row * D + lane] = y;
}

extern "C" void kernel_launch(void* const* d_in, const int* in_sizes, int n_in,
                              void* d_out, int out_size, void* d_ws, size_t ws_size,
                              hipStream_t stream) {
    const float* feat_lit = (const float*)d_in[0];
    const float* feat_cls = (const float*)d_in[1];
    const int*   lit_idx  = (const int*)d_in[2];
    const int*   cls_idx  = (const int*)d_in[3];
    const float* W_l2c    = (const float*)d_in[4];
    const float* b_l2c    = (const float*)d_in[5];
    const float* W_c2l    = (const float*)d_in[6];
    const float* b_c2l    = (const float*)d_in[7];

    const int n_lit   = in_sizes[0] / D;
    const int n_cls   = in_sizes[1] / D;
    const int n_edges = in_sizes[2];
    const int noff    = n_cls + n_lit;

    float* out_hlit = (float*)d_out;               // [n_lit, D]
    float* out_h2   = out_hlit + (long)n_lit * D;  // [n_cls, D]

    // ---- workspace layout ----
    // off:    (noff+1) ints   (doubles as cnt before scan)
    // cursor: noff ints
    // partial: 256 ints
    // edge_buf: 2*n_edges ints
    // cembs:  n_cls*D floats
    char* w = (char*)d_ws;
    int* off     = (int*)w;                 w += (size_t)(noff + 1) * 4;
    int* cursor  = (int*)w;                 w += (size_t)noff * 4;
    int* partial = (int*)w;                 w += 256 * 4;
    int* edge_buf= (int*)w;                 w += (size_t)2 * n_edges * 4;
    // align cembs to 16B
    w = (char*)(((size_t)w + 15) & ~(size_t)15);
    float* cembs = (float*)w;

    const int GB = 2048, BT = 256;
    const int nb_scan = (noff + 4095) / 4096;  // <= 256 required

    // 1. zero degree counters (off array used as cnt)
    k_zero<<<(noff / 4 + 255) / 256 + 1, BT, 0, stream>>>((float*)off, noff);
    // 2. histogram
    k_hist<<<GB, BT, 0, stream>>>(lit_idx, cls_idx, off, n_edges, n_cls);
    // 3-5. exclusive scan (in place) + cursor copy + sentinel
    k_scan1<<<nb_scan, BT, 0, stream>>>(off, partial, noff);
    k_scan2<<<1, BT, 0, stream>>>(partial, nb_scan, off, noff);
    k_scan3<<<GB, BT, 0, stream>>>(off, partial, cursor, noff);
    // 6. fill CSR edge lists (clause lists then literal lists in one buffer)
    k_fill<<<GB, BT, 0, stream>>>(lit_idx, cls_idx, cursor, edge_buf, n_edges, n_cls);

    // 7. h2_clause = relu(feat_clause @ W_l2c + b_l2c)  (independent)
    k_linear<<<GB, BT, 0, stream>>>(feat_cls, W_l2c, b_l2c, out_h2, n_cls, 1);

    // 8. cembs = relu( mean_lit(feat_literal) @ W_l2c + b_l2c )
    k_agg<<<(n_cls + 3) / 4, BT, 0, stream>>>(feat_lit, off, edge_buf,
                                              W_l2c, b_l2c, cembs, n_cls, 1);
    // 9. h_lit = mean_cls(cembs) @ W_c2l + b_c2l
    k_agg<<<(n_lit + 3) / 4, BT, 0, stream>>>(cembs, off + n_cls, edge_buf,
                                              W_c2l, b_c2l, out_hlit, n_lit, 0);
}

// Round 3
// 1361.767 us; speedup vs baseline: 1.5186x; 1.1950x over previous
//
#include <hip/hip_runtime.h>

#define D 64
#define NXCD 8

__device__ __forceinline__ float bf2f(unsigned short u) {
    union { unsigned int i; float f; } v; v.i = ((unsigned int)u) << 16; return v.f;
}
__device__ __forceinline__ unsigned short f2bf(float f) {
    union { float f; unsigned int i; } v; v.f = f;
    unsigned int r = v.i + 0x7FFFu + ((v.i >> 16) & 1u);  // RNE
    return (unsigned short)(r >> 16);
}

// ---------------------------------------------------------------- zero fill
__global__ __launch_bounds__(256) void k_zero(float* __restrict__ p, long n) {
    long i = (long)blockIdx.x * blockDim.x + threadIdx.x;
    long stride = (long)gridDim.x * blockDim.x;
    long n4 = n >> 2;
    float4* p4 = (float4*)p;
    for (long j = i; j < n4; j += stride) p4[j] = make_float4(0.f, 0.f, 0.f, 0.f);
    long tail = n4 << 2;
    for (long j = tail + i; j < n; j += stride) p[j] = 0.f;
}

// ------------------------------------------- f32 -> bf16 convert (4/thread)
__global__ __launch_bounds__(256) void k_f2bf(const float* __restrict__ in,
                                              unsigned short* __restrict__ out,
                                              long n4) {  // n/4
    long i = (long)blockIdx.x * blockDim.x + threadIdx.x;
    long stride = (long)gridDim.x * blockDim.x;
    const float4* in4 = (const float4*)in;
    ushort4* out4 = (ushort4*)out;
    for (; i < n4; i += stride) {
        float4 v = in4[i];
        ushort4 o;
        o.x = f2bf(v.x); o.y = f2bf(v.y); o.z = f2bf(v.z); o.w = f2bf(v.w);
        out4[i] = o;
    }
}

// ------------------- XCD-pinned degree histogram: block group b&7 owns tile
__global__ __launch_bounds__(256) void k_hist_p(const int* __restrict__ lit_idx,
                                                const int* __restrict__ cls_idx,
                                                int* __restrict__ cnt,  // [n_cls+n_lit]
                                                int n_edges, int n_cls, int n_lit) {
    int x = blockIdx.x & (NXCD - 1);
    int tsz_c = (n_cls + NXCD - 1) / NXCD;
    int tsz_l = (n_lit + NXCD - 1) / NXCD;
    int clo = x * tsz_c, chi = min(clo + tsz_c, n_cls);
    int llo = x * tsz_l, lhi = min(llo + tsz_l, n_lit);
    long i = (long)(blockIdx.x >> 3) * blockDim.x + threadIdx.x;
    long stride = (long)(gridDim.x >> 3) * blockDim.x;
    for (; i < n_edges; i += stride) {
        int c = cls_idx[i];
        int l = lit_idx[i];
        if (c >= clo && c < chi) atomicAdd(&cnt[c], 1);
        if (l >= llo && l < lhi) atomicAdd(&cnt[n_cls + l], 1);
    }
}

// ------------------- hierarchical exclusive scan: pass 1 (4096 elems/block)
__global__ __launch_bounds__(256) void k_scan1(int* __restrict__ data,
                                               int* __restrict__ partial,
                                               int n) {
    __shared__ int wsum[4];
    int base = blockIdx.x * 4096 + threadIdx.x * 16;
    int v[16];
    int tsum = 0;
#pragma unroll
    for (int j = 0; j < 16; ++j) {
        int idx = base + j;
        v[j] = (idx < n) ? data[idx] : 0;
        tsum += v[j];
    }
    int lane = threadIdx.x & 63;
    int wid = threadIdx.x >> 6;
    int incl = tsum;
    for (int d = 1; d < 64; d <<= 1) {
        int t = __shfl_up(incl, d);
        if (lane >= d) incl += t;
    }
    if (lane == 63) wsum[wid] = incl;
    __syncthreads();
    int wbase = 0;
    for (int w = 0; w < wid; ++w) wbase += wsum[w];
    int run = wbase + incl - tsum;
#pragma unroll
    for (int j = 0; j < 16; ++j) {
        int idx = base + j;
        if (idx < n) data[idx] = run;
        run += v[j];
    }
    if (threadIdx.x == 255) partial[blockIdx.x] = wbase + incl;
}

__global__ __launch_bounds__(256) void k_scan2(int* __restrict__ partial, int nb,
                                               int* __restrict__ off, int n) {
    __shared__ int wsum[4];
    int tid = threadIdx.x;
    int v = (tid < nb) ? partial[tid] : 0;
    int lane = tid & 63, wid = tid >> 6;
    int incl = v;
    for (int d = 1; d < 64; d <<= 1) {
        int t = __shfl_up(incl, d);
        if (lane >= d) incl += t;
    }
    if (lane == 63) wsum[wid] = incl;
    __syncthreads();
    int wbase = 0;
    for (int w = 0; w < wid; ++w) wbase += wsum[w];
    if (tid < nb) partial[tid] = wbase + incl - v;
    if (tid == 255) off[n] = wbase + incl;
}

__global__ __launch_bounds__(256) void k_scan3(int* __restrict__ off,
                                               const int* __restrict__ partial,
                                               int* __restrict__ cursor, int n) {
    long i = (long)blockIdx.x * blockDim.x + threadIdx.x;
    long stride = (long)gridDim.x * blockDim.x;
    for (; i < n; i += stride) {
        int o = off[i] + partial[i >> 12];
        off[i] = o;
        cursor[i] = o;
    }
}

// ------------------- XCD-pinned CSR fill
__global__ __launch_bounds__(256) void k_fill_p(const int* __restrict__ lit_idx,
                                                const int* __restrict__ cls_idx,
                                                int* __restrict__ cursor,
                                                int* __restrict__ edge_buf,
                                                int n_edges, int n_cls, int n_lit) {
    int x = blockIdx.x & (NXCD - 1);
    int tsz_c = (n_cls + NXCD - 1) / NXCD;
    int tsz_l = (n_lit + NXCD - 1) / NXCD;
    int clo = x * tsz_c, chi = min(clo + tsz_c, n_cls);
    int llo = x * tsz_l, lhi = min(llo + tsz_l, n_lit);
    long i = (long)(blockIdx.x >> 3) * blockDim.x + threadIdx.x;
    long stride = (long)(gridDim.x >> 3) * blockDim.x;
    for (; i < n_edges; i += stride) {
        int c = cls_idx[i];
        int l = lit_idx[i];
        if (c >= clo && c < chi) {
            int p = atomicAdd(&cursor[c], 1);
            edge_buf[p] = l;
        }
        if (l >= llo && l < lhi) {
            int q = atomicAdd(&cursor[n_cls + l], 1);
            edge_buf[q] = c;
        }
    }
}

// ------------------------------------------------- Y = X @ W + b, opt. relu
__global__ __launch_bounds__(256) void k_linear(const float* __restrict__ X,
                                                const float* __restrict__ W,
                                                const float* __restrict__ b,
                                                float* __restrict__ Y,
                                                int nrows, int do_relu) {
    __shared__ float Wl[D * D];
    __shared__ float bl[D];
    for (int i = threadIdx.x; i < D * D; i += 256) Wl[i] = W[i];
    if (threadIdx.x < D) bl[threadIdx.x] = b[threadIdx.x];
    __syncthreads();
    int lane = threadIdx.x & 63;
    int lrow = threadIdx.x >> 6;
    for (int row = blockIdx.x * 4 + lrow; row < nrows; row += gridDim.x * 4) {
        const float4* x4 = (const float4*)(X + (long)row * D);
        float acc = bl[lane];
#pragma unroll
        for (int k4 = 0; k4 < D / 4; ++k4) {
            float4 xv = x4[k4];
            acc += xv.x * Wl[(k4 * 4 + 0) * D + lane];
            acc += xv.y * Wl[(k4 * 4 + 1) * D + lane];
            acc += xv.z * Wl[(k4 * 4 + 2) * D + lane];
            acc += xv.w * Wl[(k4 * 4 + 3) * D + lane];
        }
        if (do_relu) acc = fmaxf(acc, 0.f);
        Y[(long)row * D + lane] = acc;
    }
}

// ------- gather-mean (bf16 src) over CSR row, fused 64x64 f32 linear
__global__ __launch_bounds__(256) void k_agg_bf(const unsigned short* __restrict__ src,
                                                const int* __restrict__ off,
                                                const int* __restrict__ edges,
                                                const float* __restrict__ W,
                                                const float* __restrict__ bias,
                                                void* __restrict__ out,
                                                int nrows, int relu_out, int out_bf) {
    __shared__ float Wl[D * D];
    __shared__ float bl[D];
    for (int i = threadIdx.x; i < D * D; i += 256) Wl[i] = W[i];
    if (threadIdx.x < D) bl[threadIdx.x] = bias[threadIdx.x];
    __syncthreads();
    int lane = threadIdx.x & 63;
    int wrow = threadIdx.x >> 6;
    int row = blockIdx.x * 4 + wrow;
    if (row >= nrows) return;
    int s = off[row], e = off[row + 1];
    int cnt = e - s;
    float acc = 0.f;
    for (int base = s; base < e; base += 64) {
        int nn = min(64, e - base);
        int myidx = (base + lane < e) ? edges[base + lane] : 0;
        for (int j = 0; j < nn; ++j) {
            int c = __shfl(myidx, j);
            acc += bf2f(src[(long)c * D + lane]);
        }
    }
    float m = (cnt > 0) ? acc / (float)cnt : 0.f;
    float y = bl[lane];
#pragma unroll
    for (int k = 0; k < D; ++k) y += __shfl(m, k) * Wl[k * D + lane];
    if (cnt == 0) y = 0.f;
    if (relu_out) y = fmaxf(y, 0.f);
    if (out_bf) ((unsigned short*)out)[(long)row * D + lane] = f2bf(y);
    else        ((float*)out)[(long)row * D + lane] = y;
}

extern "C" void kernel_launch(void* const* d_in, const int* in_sizes, int n_in,
                              void* d_out, int out_size, void* d_ws, size_t ws_size,
                              hipStream_t stream) {
    const float* feat_lit = (const float*)d_in[0];
    const float* feat_cls = (const float*)d_in[1];
    const int*   lit_idx  = (const int*)d_in[2];
    const int*   cls_idx  = (const int*)d_in[3];
    const float* W_l2c    = (const float*)d_in[4];
    const float* b_l2c    = (const float*)d_in[5];
    const float* W_c2l    = (const float*)d_in[6];
    const float* b_c2l    = (const float*)d_in[7];

    const int n_lit   = in_sizes[0] / D;
    const int n_cls   = in_sizes[1] / D;
    const int n_edges = in_sizes[2];
    const int noff    = n_cls + n_lit;

    float* out_hlit = (float*)d_out;               // [n_lit, D]
    float* out_h2   = out_hlit + (long)n_lit * D;  // [n_cls, D]

    // ---- workspace layout ----
    char* w = (char*)d_ws;
    int* off      = (int*)w;  w += (size_t)(noff + 1) * 4;
    int* cursor   = (int*)w;  w += (size_t)noff * 4;
    int* partial  = (int*)w;  w += 256 * 4;
    w = (char*)(((size_t)w + 15) & ~(size_t)15);
    int* edge_buf = (int*)w;  w += (size_t)2 * n_edges * 4;
    w = (char*)(((size_t)w + 15) & ~(size_t)15);
    unsigned short* feat_lit_bf = (unsigned short*)w;  w += (size_t)n_lit * D * 2;
    w = (char*)(((size_t)w + 15) & ~(size_t)15);
    unsigned short* cembs_bf = (unsigned short*)w;

    const int GB = 2048, BT = 256;
    const int nb_scan = (noff + 4095) / 4096;  // 98 <= 256

    // 1. zero degree counters (off used as cnt)
    k_zero<<<512, BT, 0, stream>>>((float*)off, noff);
    // 2. bf16 copy of feat_literal (independent of 1)
    k_f2bf<<<GB, BT, 0, stream>>>(feat_lit, feat_lit_bf, (long)n_lit * D / 4);
    // 3. XCD-pinned histogram
    k_hist_p<<<GB, BT, 0, stream>>>(lit_idx, cls_idx, off, n_edges, n_cls, n_lit);
    // 4-6. exclusive scan + cursor copy
    k_scan1<<<nb_scan, BT, 0, stream>>>(off, partial, noff);
    k_scan2<<<1, BT, 0, stream>>>(partial, nb_scan, off, noff);
    k_scan3<<<GB, BT, 0, stream>>>(off, partial, cursor, noff);
    // 7. XCD-pinned CSR fill
    k_fill_p<<<GB, BT, 0, stream>>>(lit_idx, cls_idx, cursor, edge_buf, n_edges, n_cls, n_lit);

    // 8. h2_clause = relu(feat_clause @ W_l2c + b_l2c)   (f32, independent)
    k_linear<<<GB, BT, 0, stream>>>(feat_cls, W_l2c, b_l2c, out_h2, n_cls, 1);

    // 9. cembs(bf16) = relu( mean_lit(feat_lit_bf) @ W_l2c + b_l2c )
    k_agg_bf<<<(n_cls + 3) / 4, BT, 0, stream>>>(feat_lit_bf, off, edge_buf,
                                                 W_l2c, b_l2c, cembs_bf, n_cls, 1, 1);
    // 10. h_lit = mean_cls(cembs_bf) @ W_c2l + b_c2l   (f32 out)
    k_agg_bf<<<(n_lit + 3) / 4, BT, 0, stream>>>(cembs_bf, off + n_cls, edge_buf,
                                                 W_c2l, b_c2l, out_hlit, n_lit, 0, 0);
}